// Round 4
// baseline (719.286 us; speedup 1.0000x reference)
//
#include <hip/hip_runtime.h>

// GRU encoder: B=64, T=512, F=64, H=256, D=64.
//   k1: xproj = x @ kernel + bias -> f16 in d_ws, dot2-based GEMM (unchanged).
//   k2: per-batch scan, 64 blocks x 1024 threads, gates on waves 0-3.
//       Round-4 = round-3 retry (infra failure), hardened:
//       inner op v_pk_fma_f16 via INLINE ASM (deterministic selection),
//       group-leading product via operator* (v_pk_mul_f16), f16 pair
//       accumulators folded to f32 every 2 groups (16 k-terms) with
//       fdot2(acc, {1,1}, f32acc). h prefetch depth-1 (depth-2 was neutral).

typedef _Float16 half2_t __attribute__((ext_vector_type(2)));
typedef _Float16 f16x4_t __attribute__((ext_vector_type(4)));

#define LOG2E 1.4426950408889634f

__device__ __forceinline__ float fast_sigmoid(float x) {
  float e = __builtin_amdgcn_exp2f(-x * LOG2E);
  return __builtin_amdgcn_rcpf(1.0f + e);
}
__device__ __forceinline__ float fast_tanh(float x) {
  float e = __builtin_amdgcn_exp2f(x * (2.0f * LOG2E));
  return 1.0f - 2.0f * __builtin_amdgcn_rcpf(1.0f + e);
}

// Packed f16 FMA, acc = a*b + acc. Inline asm: guaranteed v_pk_fma_f16
// (VOP3P, natural packed form) on gfx950 -- avoids any builtin lowering
// uncertainty after the round-3 toolchain failure.
#define PK_FMA(acc, a, b) \
  asm("v_pk_fma_f16 %0, %1, %2, %0" : "+v"(acc) : "v"(a), "v"(b))

// ---------------------------------------------------------------------------
// Kernel 1: xproj GEMM.  C(32768x768) = A(32768x64) @ B(64x768) + bias.
// (unchanged)
// ---------------------------------------------------------------------------
__global__ __launch_bounds__(256, 4) void xproj_gemm(
    const float* __restrict__ x, const float* __restrict__ kmat,
    const float* __restrict__ bias, _Float16* __restrict__ xp) {
  __shared__ half2_t As2[32][132];  // [kpair][row]
  __shared__ half2_t Bs2[32][132];  // [kpair][col]
  const int tid = threadIdx.x;
  const int rb = blockIdx.x * 128;
  const int cb = blockIdx.y * 128;

  {
    const int k4 = (tid & 15) * 4;
    const int r0 = tid >> 4;
#pragma unroll
    for (int p = 0; p < 8; ++p) {
      int r = r0 + p * 16;
      float4 v = *(const float4*)(x + (size_t)(rb + r) * 64 + k4);
      half2_t lo, hi;
      lo[0] = (_Float16)v.x; lo[1] = (_Float16)v.y;
      hi[0] = (_Float16)v.z; hi[1] = (_Float16)v.w;
      As2[k4 / 2][r] = lo;
      As2[k4 / 2 + 1][r] = hi;
    }
  }
  {
    const int c4 = (tid & 31) * 4;
    const int kp0 = tid >> 5;
#pragma unroll
    for (int p = 0; p < 4; ++p) {
      int kp = kp0 + p * 8;
      float4 va = *(const float4*)(kmat + (size_t)(2 * kp) * 768 + cb + c4);
      float4 vb = *(const float4*)(kmat + (size_t)(2 * kp + 1) * 768 + cb + c4);
      half2_t o0, o1, o2, o3;
      o0[0] = (_Float16)va.x; o0[1] = (_Float16)vb.x;
      o1[0] = (_Float16)va.y; o1[1] = (_Float16)vb.y;
      o2[0] = (_Float16)va.z; o2[1] = (_Float16)vb.z;
      o3[0] = (_Float16)va.w; o3[1] = (_Float16)vb.w;
      Bs2[kp][c4 + 0] = o0;
      Bs2[kp][c4 + 1] = o1;
      Bs2[kp][c4 + 2] = o2;
      Bs2[kp][c4 + 3] = o3;
    }
  }
  __syncthreads();

  const int tx = tid & 15, ty = tid >> 4;
  const int r0 = ty * 8;
  const int c0 = tx * 4;
  float acc[8][8];
  {
    float4 b0 = *(const float4*)(bias + cb + c0);
    float4 b1 = *(const float4*)(bias + cb + 64 + c0);
    float bz[8] = {b0.x, b0.y, b0.z, b0.w, b1.x, b1.y, b1.z, b1.w};
#pragma unroll
    for (int i = 0; i < 8; ++i)
#pragma unroll
      for (int j = 0; j < 8; ++j) acc[i][j] = bz[j];
  }

#pragma unroll 2
  for (int kp = 0; kp < 32; ++kp) {
    half2_t a2[8], b2[8];
    *(int4*)(&a2[0]) = *(const int4*)(&As2[kp][r0]);
    *(int4*)(&a2[4]) = *(const int4*)(&As2[kp][r0 + 4]);
    *(int2*)(&b2[0]) = *(const int2*)(&Bs2[kp][c0]);
    *(int2*)(&b2[2]) = *(const int2*)(&Bs2[kp][c0 + 2]);
    *(int2*)(&b2[4]) = *(const int2*)(&Bs2[kp][64 + c0]);
    *(int2*)(&b2[6]) = *(const int2*)(&Bs2[kp][64 + c0 + 2]);
#pragma unroll
    for (int i = 0; i < 8; ++i)
#pragma unroll
      for (int j = 0; j < 8; ++j)
        acc[i][j] = __builtin_amdgcn_fdot2(a2[i], b2[j], acc[i][j], false);
  }

#pragma unroll
  for (int i = 0; i < 8; ++i) {
    f16x4_t o0, o1;
#pragma unroll
    for (int j = 0; j < 4; ++j) {
      o0[j] = (_Float16)acc[i][j];
      o1[j] = (_Float16)acc[i][4 + j];
    }
    _Float16* dst = xp + (size_t)(rb + r0 + i) * 768 + cb;
    *(f16x4_t*)(dst + c0) = o0;
    *(f16x4_t*)(dst + 64 + c0) = o1;
  }
}

// ---------------------------------------------------------------------------
// Kernel 2: GRU scan. One block per batch row. 1024 threads = 16 waves.
// Thread (c = tid>>8, col = tid&255) holds W_rec[k in 64c..64c+63] for
// columns {col, col+256, col+512} as 96 packed f16 pairs in VGPRs.
// Inner loop per 2 groups (8 pairs = 16 k-terms):
//   3x v_pk_mul_f16 + 21x v_pk_fma_f16 (f16 pair accumulators)
//   3x v_dot2_f32_f16 fold into f32 totals.
// part2 layout: row (gate*256+col), stride 6 floats, entry [c].
// Gates on waves 0-3 only (others branch over).
// ---------------------------------------------------------------------------
#define PKFMA12(U, J)                                    \
  do {                                                   \
    half2_t p0 = __builtin_bit_cast(half2_t, (U).x);     \
    half2_t p1 = __builtin_bit_cast(half2_t, (U).y);     \
    half2_t p2 = __builtin_bit_cast(half2_t, (U).z);     \
    half2_t p3 = __builtin_bit_cast(half2_t, (U).w);     \
    PK_FMA(c0, p0, w2[0][(J) + 0]);                      \
    PK_FMA(c0, p1, w2[0][(J) + 1]);                      \
    PK_FMA(c0, p2, w2[0][(J) + 2]);                      \
    PK_FMA(c0, p3, w2[0][(J) + 3]);                      \
    PK_FMA(c1, p0, w2[1][(J) + 0]);                      \
    PK_FMA(c1, p1, w2[1][(J) + 1]);                      \
    PK_FMA(c1, p2, w2[1][(J) + 2]);                      \
    PK_FMA(c1, p3, w2[1][(J) + 3]);                      \
    PK_FMA(c2, p0, w2[2][(J) + 0]);                      \
    PK_FMA(c2, p1, w2[2][(J) + 1]);                      \
    PK_FMA(c2, p2, w2[2][(J) + 2]);                      \
    PK_FMA(c2, p3, w2[2][(J) + 3]);                      \
  } while (0)

__global__ __launch_bounds__(1024, 4) void gru_scan(
    const _Float16* __restrict__ xp, const float* __restrict__ wr,
    const float* __restrict__ dw, const float* __restrict__ db,
    float* __restrict__ out, float* __restrict__ state) {
  __shared__ float2 part2[768 * 3];  // [(gate*256+col)*3 + pair], 18.4 KB
  __shared__ float hbuf[256];
  __shared__ alignas(16) _Float16 hhalf[256];

  const int tid = threadIdx.x;
  const int b = blockIdx.x;
  const int c = tid >> 8;     // k-chunk 0..3
  const int col = tid & 255;  // output column within gate

  // --- load W_rec fragment into registers as f16 pairs (96 VGPRs)
  half2_t w2[3][32];
#pragma unroll
  for (int q = 0; q < 3; ++q) {
    const float* wp = wr + (size_t)(c * 64) * 768 + col + q * 256;
#pragma unroll
    for (int j = 0; j < 32; ++j) {
      float wa = wp[(size_t)(2 * j) * 768];
      float wb = wp[(size_t)(2 * j + 1) * 768];
      half2_t p;
      p[0] = (_Float16)wa;
      p[1] = (_Float16)wb;
      w2[q][j] = p;
    }
  }

  if (tid < 256) hhalf[tid] = (_Float16)0.0f;
  __syncthreads();

  const _Float16* xpb = xp + (size_t)b * 512 * 768;
  float* outb = out + (size_t)b * 512 * 256;
  const int4* hp2 = (const int4*)hhalf + c * 8;
  float* pw = (float*)part2;
  float hprev = 0.0f;

  const half2_t ones = {(_Float16)1.0f, (_Float16)1.0f};

#pragma unroll 1
  for (int t = 0; t < 512; ++t) {
    // Gate waves only: deferred h(t-1) store + direct coalesced x loads.
    _Float16 x0 = (_Float16)0.0f, x1 = (_Float16)0.0f, x2 = (_Float16)0.0f;
    if (tid < 256) {
      if (t) outb[(size_t)(t - 1) * 256 + tid] = hprev;
      const _Float16* xr = xpb + (size_t)t * 768 + tid;
      x0 = xr[0];
      x1 = xr[256];
      x2 = xr[512];
    }

    float a0 = 0.0f, a1 = 0.0f, a2 = 0.0f;
    int4 hv = hp2[0];
#pragma unroll
    for (int s = 0; s < 4; ++s) {
      // First pair of the segment initializes the f16 accumulators via
      // v_pk_mul_f16; remaining 7 pairs are v_pk_fma_f16.
      half2_t q0 = __builtin_bit_cast(half2_t, hv.x);
      half2_t c0 = q0 * w2[0][s * 8];
      half2_t c1 = q0 * w2[1][s * 8];
      half2_t c2 = q0 * w2[2][s * 8];
#pragma unroll
      for (int gg = 0; gg < 2; ++gg) {
        const int g = s * 2 + gg;
        __builtin_amdgcn_sched_barrier(1);  // pin ds_reads: depth-1 prefetch
        int4 hn = hv;
        if (g < 7) hn = hp2[g + 1];
        if (gg == 0) {
          // pairs 1..3 of this int4 (pair 0 consumed by the init muls)
          half2_t p1 = __builtin_bit_cast(half2_t, hv.y);
          half2_t p2 = __builtin_bit_cast(half2_t, hv.z);
          half2_t p3 = __builtin_bit_cast(half2_t, hv.w);
          PK_FMA(c0, p1, w2[0][g * 4 + 1]);
          PK_FMA(c0, p2, w2[0][g * 4 + 2]);
          PK_FMA(c0, p3, w2[0][g * 4 + 3]);
          PK_FMA(c1, p1, w2[1][g * 4 + 1]);
          PK_FMA(c1, p2, w2[1][g * 4 + 2]);
          PK_FMA(c1, p3, w2[1][g * 4 + 3]);
          PK_FMA(c2, p1, w2[2][g * 4 + 1]);
          PK_FMA(c2, p2, w2[2][g * 4 + 2]);
          PK_FMA(c2, p3, w2[2][g * 4 + 3]);
        } else {
          PKFMA12(hv, g * 4);
        }
        hv = hn;
      }
      // fold f16 pair partials into f32 (1 instr per gate per segment)
      a0 = __builtin_amdgcn_fdot2(c0, ones, a0, false);
      a1 = __builtin_amdgcn_fdot2(c1, ones, a1, false);
      a2 = __builtin_amdgcn_fdot2(c2, ones, a2, false);
    }
    // Transposed partials: row = gate*256+col, stride 6 floats, entry c.
    pw[col * 6 + c] = a0;
    pw[1536 + col * 6 + c] = a1;
    pw[3072 + col * 6 + c] = a2;
    __syncthreads();

    // --- gates: waves 0..3 only.
    if (tid < 256) {
      const int i = tid;
      float2 z0 = part2[i * 3 + 0];
      float2 z1 = part2[i * 3 + 1];
      float2 r0 = part2[768 + i * 3 + 0];
      float2 r1 = part2[768 + i * 3 + 1];
      float2 h0 = part2[1536 + i * 3 + 0];
      float2 h1 = part2[1536 + i * 3 + 1];
      float rz = (z0.x + z0.y) + (z1.x + z1.y);
      float rr = (r0.x + r0.y) + (r1.x + r1.y);
      float rh = (h0.x + h0.y) + (h1.x + h1.y);
      float z = fast_sigmoid((float)x0 + rz);
      float r = fast_sigmoid((float)x1 + rr);
      float hh = fast_tanh((float)x2 + r * rh);
      float hnew = z * hprev + (1.0f - z) * hh;
      hprev = hnew;
      hhalf[i] = (_Float16)hnew;
    }
    __syncthreads();
  }

  if (tid < 256) {
    outb[(size_t)511 * 256 + tid] = hprev;
    hbuf[tid] = hprev;
  }
  __syncthreads();

  // --- dense head: state[b,:] = tanh(h_last @ dense_w + dense_b)
  if (tid < 64) {
    float acc = db[tid];
#pragma unroll 8
    for (int k = 0; k < 256; ++k) acc = fmaf(hbuf[k], dw[k * 64 + tid], acc);
    state[(size_t)b * 64 + tid] = fast_tanh(acc);
  }
}

// ---------------------------------------------------------------------------
extern "C" void kernel_launch(void* const* d_in, const int* in_sizes, int n_in,
                              void* d_out, int out_size, void* d_ws,
                              size_t ws_size, hipStream_t stream) {
  const float* x = (const float*)d_in[0];     // (64,512,64)
  const float* kmat = (const float*)d_in[1];  // (64,768)
  const float* wr = (const float*)d_in[2];    // (256,768)
  const float* bias = (const float*)d_in[3];  // (768,)
  const float* dw = (const float*)d_in[4];    // (256,64)
  const float* db = (const float*)d_in[5];    // (64,)

  float* out = (float*)d_out;                   // (64,512,256)
  float* state = out + (size_t)64 * 512 * 256;  // (64,64)
  _Float16* xp = (_Float16*)d_ws;               // 64*512*768 f16 = 48 MiB

  dim3 gg(32768 / 128, 768 / 128);
  xproj_gemm<<<gg, 256, 0, stream>>>(x, kmat, bias, xp);
  gru_scan<<<64, 1024, 0, stream>>>(xp, wr, dw, db, out, state);
}

// Round 5
// 660.904 us; speedup vs baseline: 1.0883x; 1.0883x over previous
//
#include <hip/hip_runtime.h>

// GRU encoder: B=64, T=512, F=64, H=256, D=64.
//   k1: xproj = x @ kernel + bias -> f16 in d_ws, dot2-based GEMM (unchanged).
//   k2: per-batch scan, 64 blocks x 1024 threads, gates on waves 0-3.
//       Round-5 delta: W_rec loads were being SUNK into the t-loop by the
//       compiler (VGPR_Count=64, FETCH_SIZE=37GB/dispatch -> re-reading all
//       768KB of W from L2 every step; ~5.4 TB/s per XCD = L2-BW-bound).
//       Fix: opaque asm "+v" on every w2 element after the setup load --
//       non-rematerializable, forces true VGPR residency. Inner loop back
//       to plain dot2 (pk_fma regressed), no prefetch dance (h reads are
//       wave-uniform LDS broadcasts; trimming movs keeps live set <=128).

typedef _Float16 half2_t __attribute__((ext_vector_type(2)));
typedef _Float16 f16x4_t __attribute__((ext_vector_type(4)));

#define LOG2E 1.4426950408889634f

__device__ __forceinline__ float fast_sigmoid(float x) {
  float e = __builtin_amdgcn_exp2f(-x * LOG2E);
  return __builtin_amdgcn_rcpf(1.0f + e);
}
__device__ __forceinline__ float fast_tanh(float x) {
  float e = __builtin_amdgcn_exp2f(x * (2.0f * LOG2E));
  return 1.0f - 2.0f * __builtin_amdgcn_rcpf(1.0f + e);
}

// ---------------------------------------------------------------------------
// Kernel 1: xproj GEMM.  C(32768x768) = A(32768x64) @ B(64x768) + bias.
// (unchanged)
// ---------------------------------------------------------------------------
__global__ __launch_bounds__(256, 4) void xproj_gemm(
    const float* __restrict__ x, const float* __restrict__ kmat,
    const float* __restrict__ bias, _Float16* __restrict__ xp) {
  __shared__ half2_t As2[32][132];  // [kpair][row]
  __shared__ half2_t Bs2[32][132];  // [kpair][col]
  const int tid = threadIdx.x;
  const int rb = blockIdx.x * 128;
  const int cb = blockIdx.y * 128;

  {
    const int k4 = (tid & 15) * 4;
    const int r0 = tid >> 4;
#pragma unroll
    for (int p = 0; p < 8; ++p) {
      int r = r0 + p * 16;
      float4 v = *(const float4*)(x + (size_t)(rb + r) * 64 + k4);
      half2_t lo, hi;
      lo[0] = (_Float16)v.x; lo[1] = (_Float16)v.y;
      hi[0] = (_Float16)v.z; hi[1] = (_Float16)v.w;
      As2[k4 / 2][r] = lo;
      As2[k4 / 2 + 1][r] = hi;
    }
  }
  {
    const int c4 = (tid & 31) * 4;
    const int kp0 = tid >> 5;
#pragma unroll
    for (int p = 0; p < 4; ++p) {
      int kp = kp0 + p * 8;
      float4 va = *(const float4*)(kmat + (size_t)(2 * kp) * 768 + cb + c4);
      float4 vb = *(const float4*)(kmat + (size_t)(2 * kp + 1) * 768 + cb + c4);
      half2_t o0, o1, o2, o3;
      o0[0] = (_Float16)va.x; o0[1] = (_Float16)vb.x;
      o1[0] = (_Float16)va.y; o1[1] = (_Float16)vb.y;
      o2[0] = (_Float16)va.z; o2[1] = (_Float16)vb.z;
      o3[0] = (_Float16)va.w; o3[1] = (_Float16)vb.w;
      Bs2[kp][c4 + 0] = o0;
      Bs2[kp][c4 + 1] = o1;
      Bs2[kp][c4 + 2] = o2;
      Bs2[kp][c4 + 3] = o3;
    }
  }
  __syncthreads();

  const int tx = tid & 15, ty = tid >> 4;
  const int r0 = ty * 8;
  const int c0 = tx * 4;
  float acc[8][8];
  {
    float4 b0 = *(const float4*)(bias + cb + c0);
    float4 b1 = *(const float4*)(bias + cb + 64 + c0);
    float bz[8] = {b0.x, b0.y, b0.z, b0.w, b1.x, b1.y, b1.z, b1.w};
#pragma unroll
    for (int i = 0; i < 8; ++i)
#pragma unroll
      for (int j = 0; j < 8; ++j) acc[i][j] = bz[j];
  }

#pragma unroll 2
  for (int kp = 0; kp < 32; ++kp) {
    half2_t a2[8], b2[8];
    *(int4*)(&a2[0]) = *(const int4*)(&As2[kp][r0]);
    *(int4*)(&a2[4]) = *(const int4*)(&As2[kp][r0 + 4]);
    *(int2*)(&b2[0]) = *(const int2*)(&Bs2[kp][c0]);
    *(int2*)(&b2[2]) = *(const int2*)(&Bs2[kp][c0 + 2]);
    *(int2*)(&b2[4]) = *(const int2*)(&Bs2[kp][64 + c0]);
    *(int2*)(&b2[6]) = *(const int2*)(&Bs2[kp][64 + c0 + 2]);
#pragma unroll
    for (int i = 0; i < 8; ++i)
#pragma unroll
      for (int j = 0; j < 8; ++j)
        acc[i][j] = __builtin_amdgcn_fdot2(a2[i], b2[j], acc[i][j], false);
  }

#pragma unroll
  for (int i = 0; i < 8; ++i) {
    f16x4_t o0, o1;
#pragma unroll
    for (int j = 0; j < 4; ++j) {
      o0[j] = (_Float16)acc[i][j];
      o1[j] = (_Float16)acc[i][4 + j];
    }
    _Float16* dst = xp + (size_t)(rb + r0 + i) * 768 + cb;
    *(f16x4_t*)(dst + c0) = o0;
    *(f16x4_t*)(dst + 64 + c0) = o1;
  }
}

// ---------------------------------------------------------------------------
// Kernel 2: GRU scan. One block per batch row. 1024 threads = 16 waves.
// Thread (c = tid>>8, col = tid&255) holds W_rec[k in 64c..64c+63] for
// columns {col, col+256, col+512} as 96 packed f16 pairs in VGPRs --
// FORCED resident via opaque asm (compiler was re-loading W from L2 every
// step: 25 GB/dispatch of L2 traffic, the real bottleneck).
// h reads are wave-uniform LDS broadcasts (cheap, no prefetch needed).
// part2 layout: row (gate*256+col), stride 6 floats, entry [c].
// ---------------------------------------------------------------------------
__global__ __launch_bounds__(1024, 4) void gru_scan(
    const _Float16* __restrict__ xp, const float* __restrict__ wr,
    const float* __restrict__ dw, const float* __restrict__ db,
    float* __restrict__ out, float* __restrict__ state) {
  __shared__ float2 part2[768 * 3];  // [(gate*256+col)*3 + pair], 18.4 KB
  __shared__ float hbuf[256];
  __shared__ alignas(16) _Float16 hhalf[256];

  const int tid = threadIdx.x;
  const int b = blockIdx.x;
  const int c = tid >> 8;     // k-chunk 0..3
  const int col = tid & 255;  // output column within gate

  // --- load W_rec fragment as f16 pairs; force true register residency.
  half2_t w2[3][32];
#pragma unroll
  for (int q = 0; q < 3; ++q) {
    const float* wp = wr + (size_t)(c * 64) * 768 + col + q * 256;
#pragma unroll
    for (int j = 0; j < 32; ++j) {
      float wa = wp[(size_t)(2 * j) * 768];
      float wb = wp[(size_t)(2 * j + 1) * 768];
      half2_t p;
      p[0] = (_Float16)wa;
      p[1] = (_Float16)wb;
      w2[q][j] = p;
    }
  }
  // Opaque pass-through: result of asm cannot be rematerialized, so the
  // 96 values must stay live in VGPRs across the whole t-loop.
#pragma unroll
  for (int q = 0; q < 3; ++q)
#pragma unroll
    for (int j = 0; j < 32; ++j) asm volatile("" : "+v"(w2[q][j]));

  if (tid < 256) hhalf[tid] = (_Float16)0.0f;
  __syncthreads();

  const _Float16* xpb = xp + (size_t)b * 512 * 768;
  float* outb = out + (size_t)b * 512 * 256;
  const int4* hp2 = (const int4*)hhalf + c * 8;
  float* pw = (float*)part2;
  float hprev = 0.0f;

#pragma unroll 1
  for (int t = 0; t < 512; ++t) {
    // Gate waves only: deferred h(t-1) store + direct coalesced x loads.
    _Float16 x0 = (_Float16)0.0f, x1 = (_Float16)0.0f, x2 = (_Float16)0.0f;
    if (tid < 256) {
      if (t) outb[(size_t)(t - 1) * 256 + tid] = hprev;
      const _Float16* xr = xpb + (size_t)t * 768 + tid;
      x0 = xr[0];
      x1 = xr[256];
      x2 = xr[512];
    }

    float a0 = 0.0f, a1 = 0.0f, a2 = 0.0f;
#pragma unroll
    for (int g = 0; g < 8; ++g) {
      int4 hv = hp2[g];  // wave-uniform broadcast read
      half2_t p0 = __builtin_bit_cast(half2_t, hv.x);
      half2_t p1 = __builtin_bit_cast(half2_t, hv.y);
      half2_t p2 = __builtin_bit_cast(half2_t, hv.z);
      half2_t p3 = __builtin_bit_cast(half2_t, hv.w);
      a0 = __builtin_amdgcn_fdot2(p0, w2[0][g * 4 + 0], a0, false);
      a0 = __builtin_amdgcn_fdot2(p1, w2[0][g * 4 + 1], a0, false);
      a0 = __builtin_amdgcn_fdot2(p2, w2[0][g * 4 + 2], a0, false);
      a0 = __builtin_amdgcn_fdot2(p3, w2[0][g * 4 + 3], a0, false);
      a1 = __builtin_amdgcn_fdot2(p0, w2[1][g * 4 + 0], a1, false);
      a1 = __builtin_amdgcn_fdot2(p1, w2[1][g * 4 + 1], a1, false);
      a1 = __builtin_amdgcn_fdot2(p2, w2[1][g * 4 + 2], a1, false);
      a1 = __builtin_amdgcn_fdot2(p3, w2[1][g * 4 + 3], a1, false);
      a2 = __builtin_amdgcn_fdot2(p0, w2[2][g * 4 + 0], a2, false);
      a2 = __builtin_amdgcn_fdot2(p1, w2[2][g * 4 + 1], a2, false);
      a2 = __builtin_amdgcn_fdot2(p2, w2[2][g * 4 + 2], a2, false);
      a2 = __builtin_amdgcn_fdot2(p3, w2[2][g * 4 + 3], a2, false);
    }
    // Transposed partials: row = gate*256+col, stride 6 floats, entry c.
    pw[col * 6 + c] = a0;
    pw[1536 + col * 6 + c] = a1;
    pw[3072 + col * 6 + c] = a2;
    __syncthreads();

    // --- gates: waves 0..3 only.
    if (tid < 256) {
      const int i = tid;
      float2 z0 = part2[i * 3 + 0];
      float2 z1 = part2[i * 3 + 1];
      float2 r0 = part2[768 + i * 3 + 0];
      float2 r1 = part2[768 + i * 3 + 1];
      float2 h0 = part2[1536 + i * 3 + 0];
      float2 h1 = part2[1536 + i * 3 + 1];
      float rz = (z0.x + z0.y) + (z1.x + z1.y);
      float rr = (r0.x + r0.y) + (r1.x + r1.y);
      float rh = (h0.x + h0.y) + (h1.x + h1.y);
      float z = fast_sigmoid((float)x0 + rz);
      float r = fast_sigmoid((float)x1 + rr);
      float hh = fast_tanh((float)x2 + r * rh);
      float hnew = z * hprev + (1.0f - z) * hh;
      hprev = hnew;
      hhalf[i] = (_Float16)hnew;
    }
    __syncthreads();
  }

  if (tid < 256) {
    outb[(size_t)511 * 256 + tid] = hprev;
    hbuf[tid] = hprev;
  }
  __syncthreads();

  // --- dense head: state[b,:] = tanh(h_last @ dense_w + dense_b)
  if (tid < 64) {
    float acc = db[tid];
#pragma unroll 8
    for (int k = 0; k < 256; ++k) acc = fmaf(hbuf[k], dw[k * 64 + tid], acc);
    state[(size_t)b * 64 + tid] = fast_tanh(acc);
  }
}

// ---------------------------------------------------------------------------
extern "C" void kernel_launch(void* const* d_in, const int* in_sizes, int n_in,
                              void* d_out, int out_size, void* d_ws,
                              size_t ws_size, hipStream_t stream) {
  const float* x = (const float*)d_in[0];     // (64,512,64)
  const float* kmat = (const float*)d_in[1];  // (64,768)
  const float* wr = (const float*)d_in[2];    // (256,768)
  const float* bias = (const float*)d_in[3];  // (768,)
  const float* dw = (const float*)d_in[4];    // (256,64)
  const float* db = (const float*)d_in[5];    // (64,)

  float* out = (float*)d_out;                   // (64,512,256)
  float* state = out + (size_t)64 * 512 * 256;  // (64,64)
  _Float16* xp = (_Float16*)d_ws;               // 64*512*768 f16 = 48 MiB

  dim3 gg(32768 / 128, 768 / 128);
  xproj_gemm<<<gg, 256, 0, stream>>>(x, kmat, bias, xp);
  gru_scan<<<64, 1024, 0, stream>>>(xp, wr, dw, db, out, state);
}